// Round 1
// baseline (365.880 us; speedup 1.0000x reference)
//
#include <hip/hip_runtime.h>
#include <cmath>

#define NNODES 8192
#define NB 64
#define ND 5
#define NF 16
#define NHC 16
#define NE (NNODES*(ND+1))

// ---------------- CSR build (reverse graph: in-edges per dst) ----------------

__global__ void k_init_cnt(int* __restrict__ cnt) {
  int i = blockIdx.x*blockDim.x + threadIdx.x;
  if (i < NNODES) cnt[i] = 1;  // self-loop
}

__global__ void k_count(const int* __restrict__ nbr, int* __restrict__ cnt) {
  int i = blockIdx.x*blockDim.x + threadIdx.x;
  if (i < NNODES*ND) atomicAdd(&cnt[nbr[i]], 1);
}

__global__ void k_scan(const int* __restrict__ cnt, int* __restrict__ offs, int* __restrict__ cursor) {
  __shared__ int part[256];
  int t = threadIdx.x;
  const int chunk = NNODES/256;
  int base = t*chunk;
  int s = 0;
  for (int i = 0; i < chunk; ++i) s += cnt[base+i];
  part[t] = s;
  __syncthreads();
  for (int off = 1; off < 256; off <<= 1) {
    int v = (t >= off) ? part[t-off] : 0;
    __syncthreads();
    part[t] += v;
    __syncthreads();
  }
  int run = (t == 0) ? 0 : part[t-1];
  for (int i = 0; i < chunk; ++i) {
    offs[base+i] = run;
    cursor[base+i] = run;
    run += cnt[base+i];
  }
  if (t == 255) offs[NNODES] = run;
}

__global__ void k_fill(const int* __restrict__ nbr, int* __restrict__ cursor, int* __restrict__ srcl) {
  int i = blockIdx.x*blockDim.x + threadIdx.x;
  if (i >= NE) return;
  int u, v;
  if (i < NNODES*ND) { u = i/ND; v = nbr[i]; }
  else               { u = i - NNODES*ND; v = u; }
  int pos = atomicAdd(&cursor[v], 1);
  srcl[pos] = u;
}

// ---------------- per-layer: xl = h @ Wl  ([N][B][16] layout, lane=b) ----------------

template<bool BMAJOR>
__global__ void k_transform(const float* __restrict__ hin, const float* __restrict__ W,
                            float* __restrict__ xl) {
  int gid = blockIdx.x*blockDim.x + threadIdx.x;
  int n = gid >> 6;
  int b = gid & 63;
  const float* src = BMAJOR ? (hin + ((size_t)b*NNODES + n)*NF)
                            : (hin + ((size_t)n*NB + b)*NF);
  float h[16];
  #pragma unroll
  for (int q = 0; q < 4; ++q) *(float4*)(h+4*q) = ((const float4*)src)[q];
  float acc[16];
  #pragma unroll
  for (int j = 0; j < 16; ++j) acc[j] = 0.f;
  for (int f = 0; f < 16; ++f) {       // W is wave-uniform -> scalar loads
    float hf = h[f];
    #pragma unroll
    for (int j = 0; j < 16; ++j) acc[j] = fmaf(hf, W[f*16+j], acc[j]);
  }
  float* dst = xl + ((size_t)n*NB + b)*NHC;
  #pragma unroll
  for (int q = 0; q < 4; ++q) ((float4*)dst)[q] = *(float4*)(acc+4*q);
}

// ---------------- per-layer: per-dst online-softmax aggregation ----------------
// wave = one dst node v, lane = batch b. Gathers xl[u] as contiguous 4KB/wave.

template<bool BMAJOR>
__global__ void k_aggregate(const float* __restrict__ hin, const float* __restrict__ xl,
                            const float* __restrict__ Wr, const float* __restrict__ att,
                            const float* __restrict__ bias,
                            const int* __restrict__ offs, const int* __restrict__ srcl,
                            float* __restrict__ hout) {
  int gid = blockIdx.x*blockDim.x + threadIdx.x;
  int v = gid >> 6;
  int b = gid & 63;
  const float* src = BMAJOR ? (hin + ((size_t)b*NNODES + v)*NF)
                            : (hin + ((size_t)v*NB + b)*NF);
  float h[16];
  #pragma unroll
  for (int q = 0; q < 4; ++q) *(float4*)(h+4*q) = ((const float4*)src)[q];
  float xr[16];
  #pragma unroll
  for (int j = 0; j < 16; ++j) xr[j] = 0.f;
  for (int f = 0; f < 16; ++f) {       // Wr wave-uniform
    float hf = h[f];
    #pragma unroll
    for (int j = 0; j < 16; ++j) xr[j] = fmaf(hf, Wr[f*16+j], xr[j]);
  }
  float aw[16];
  #pragma unroll
  for (int j = 0; j < 16; ++j) aw[j] = att[j];

  float m[4], s[4], acc[16];
  #pragma unroll
  for (int hh = 0; hh < 4; ++hh) { m[hh] = -INFINITY; s[hh] = 0.f; }
  #pragma unroll
  for (int j = 0; j < 16; ++j) acc[j] = 0.f;

  int e0 = offs[v], e1 = offs[v+1];
  for (int e = e0; e < e1; ++e) {
    int u = srcl[e];                             // wave-uniform
    const float* sp = xl + ((size_t)u*NB + b)*NHC;
    float t[16];
    #pragma unroll
    for (int q = 0; q < 4; ++q) *(float4*)(t+4*q) = ((const float4*)sp)[q];
    #pragma unroll
    for (int hh = 0; hh < 4; ++hh) {
      float lg = 0.f;
      #pragma unroll
      for (int c = 0; c < 4; ++c) {
        float z = t[hh*4+c] + xr[hh*4+c];
        z = (z >= 0.f) ? z : 0.2f*z;             // leaky_relu, slope 0.2
        lg = fmaf(z, aw[hh*4+c], lg);
      }
      float nm = fmaxf(m[hh], lg);
      float corr = __expf(m[hh]-nm);             // exp(-inf)=0 on first edge
      float p = __expf(lg-nm);
      s[hh] = fmaf(s[hh], corr, p);
      #pragma unroll
      for (int c = 0; c < 4; ++c)
        acc[hh*4+c] = fmaf(acc[hh*4+c], corr, p*t[hh*4+c]);
      m[hh] = nm;
    }
  }

  float o[16];
  #pragma unroll
  for (int hh = 0; hh < 4; ++hh) {
    float inv = 1.f/(s[hh]+1e-16f);
    #pragma unroll
    for (int c = 0; c < 4; ++c) o[hh*4+c] = acc[hh*4+c]*inv + bias[hh*4+c];
  }
  float* dst = hout + ((size_t)v*NB + b)*NHC;
  #pragma unroll
  for (int q = 0; q < 4; ++q) ((float4*)dst)[q] = *(float4*)(o+4*q);
}

// ---------------- mean over nodes + 2-layer tanh MLP -> agg[B][64] ----------------

__global__ void __launch_bounds__(1024)
k_agg(const float* __restrict__ h, const float* __restrict__ Wg1, const float* __restrict__ bg1,
      const float* __restrict__ Wg2, const float* __restrict__ bg2, float* __restrict__ agg) {
  int b = blockIdx.x;
  int t = threadIdx.x;                 // 1024 threads
  int hc = t & 15, chunk = t >> 4;     // 64 chunks of 128 nodes
  float s = 0.f;
  for (int i = 0; i < NNODES/64; ++i) {
    int n = chunk*(NNODES/64) + i;
    s += h[((size_t)n*NB + b)*NHC + hc];
  }
  __shared__ float red[1024];
  red[t] = s;
  __syncthreads();
  for (int off = 512; off >= 16; off >>= 1) {
    if (t < off) red[t] += red[t+off];
    __syncthreads();
  }
  __shared__ float mean[16], g1[32];
  if (t < 16) mean[t] = red[t] * (1.0f/NNODES);
  __syncthreads();
  if (t < 32) {
    float a = bg1[t];
    for (int f = 0; f < 16; ++f) a = fmaf(mean[f], Wg1[f*32+t], a);
    g1[t] = tanhf(a);
  }
  __syncthreads();
  if (t < 64) {
    float a = bg2[t];
    for (int f = 0; f < 32; ++f) a = fmaf(g1[f], Wg2[f*64+t], a);
    agg[b*64+t] = tanhf(a);
  }
}

// ---------------- final edge-scoring MLP: feats(99) -> 16 -> 8 -> 1 ----------------

__global__ void k_final(const float* __restrict__ h, const int* __restrict__ agent,
                        const int* __restrict__ nbr, const float* __restrict__ agg,
                        const float* __restrict__ We1, const float* __restrict__ be1,
                        const float* __restrict__ We2, const float* __restrict__ be2,
                        const float* __restrict__ We3, const float* __restrict__ be3,
                        float* __restrict__ out) {
  int b = blockIdx.x;
  int t = threadIdx.x;                 // 256
  __shared__ float srcv[16];
  __shared__ float tgt[5][16];
  __shared__ float aggs[64];
  __shared__ float e1s[15][16];
  __shared__ float e2s[15][8];
  int an = agent[b];
  if (t < 16) srcv[t] = h[((size_t)an*NB + b)*NHC + t];
  if (t >= 32 && t < 112) {
    int d = (t-32)/16, k = (t-32)%16;
    int nn = nbr[an*ND + d];
    tgt[d][k] = h[((size_t)nn*NB + b)*NHC + k];
  }
  if (t >= 128 && t < 192) aggs[t-128] = agg[b*64 + (t-128)];
  __syncthreads();
  if (t < 240) {
    int j = t & 15, td = t >> 4;       // td = tk*5+d
    int tk = td/5, d = td%5;
    float a = be1[j];
    for (int k = 0; k < 16; ++k) a = fmaf(srcv[k],  We1[k*16+j],      a);
    a += We1[(16+tk)*16 + j];          // one-hot token rows 16..18
    for (int k = 0; k < 16; ++k) a = fmaf(tgt[d][k], We1[(19+k)*16+j], a);
    for (int k = 0; k < 64; ++k) a = fmaf(aggs[k],  We1[(35+k)*16+j], a);
    e1s[td][j] = tanhf(a);
  }
  __syncthreads();
  if (t < 120) {
    int j = t & 7, td = t >> 3;
    float a = be2[j];
    for (int k = 0; k < 16; ++k) a = fmaf(e1s[td][k], We2[k*8+j], a);
    e2s[td][j] = tanhf(a);
  }
  __syncthreads();
  if (t < 15) {
    float a = be3[0];
    for (int k = 0; k < 8; ++k) a = fmaf(e2s[t][k], We3[k], a);
    out[b*15 + t] = a;
  }
}

// ---------------- launch ----------------

extern "C" void kernel_launch(void* const* d_in, const int* in_sizes, int n_in,
                              void* d_out, int out_size, void* d_ws, size_t ws_size,
                              hipStream_t stream) {
  const float* x     = (const float*)d_in[0];
  const int*   agent = (const int*)  d_in[1];
  const int*   nbr   = (const int*)  d_in[2];
  const float* Wl    = (const float*)d_in[3];   // (4,16,4,4)
  const float* Wr    = (const float*)d_in[4];
  const float* att   = (const float*)d_in[5];   // (4,4,4)
  const float* bias  = (const float*)d_in[6];   // (4,16)
  const float* Wg1   = (const float*)d_in[7];
  const float* bg1   = (const float*)d_in[8];
  const float* Wg2   = (const float*)d_in[9];
  const float* bg2   = (const float*)d_in[10];
  const float* We1   = (const float*)d_in[11];
  const float* be1   = (const float*)d_in[12];
  const float* We2   = (const float*)d_in[13];
  const float* be2   = (const float*)d_in[14];
  const float* We3   = (const float*)d_in[15];
  const float* be3   = (const float*)d_in[16];
  float* out = (float*)d_out;

  char* ws = (char*)d_ws;
  size_t off = 0;
  auto alloc = [&](size_t bytes) -> void* {
    void* p = ws + off;
    off += (bytes + 255) & ~(size_t)255;
    return p;
  };
  const size_t HBYTES = (size_t)NNODES*NB*NHC*sizeof(float);   // 32 MB
  float* hA   = (float*)alloc(HBYTES);
  float* hB   = (float*)alloc(HBYTES);
  float* xl   = (float*)alloc(HBYTES);
  int* cnt    = (int*)alloc(NNODES*sizeof(int));
  int* offs   = (int*)alloc((NNODES+1)*sizeof(int));
  int* cursor = (int*)alloc(NNODES*sizeof(int));
  int* srcl   = (int*)alloc(NE*sizeof(int));
  float* aggb = (float*)alloc(NB*64*sizeof(float));

  // CSR build
  k_init_cnt<<<NNODES/256, 256, 0, stream>>>(cnt);
  k_count<<<(NNODES*ND+255)/256, 256, 0, stream>>>(nbr, cnt);
  k_scan<<<1, 256, 0, stream>>>(cnt, offs, cursor);
  k_fill<<<(NE+255)/256, 256, 0, stream>>>(nbr, cursor, srcl);

  const int NTH = NNODES*NB;          // one thread per (node, batch)
  const int NBLK = NTH/256;           // 2048

  // layer 0 (input x is (B,N,F) b-major)
  k_transform<true><<<NBLK, 256, 0, stream>>>(x, Wl, xl);
  k_aggregate<true><<<NBLK, 256, 0, stream>>>(x, xl, Wr, att, bias, offs, srcl, hA);
  // layers 1..3 on [N][B][16]
  const float* hin = hA;
  float* hout = hB;
  for (int l = 1; l < 4; ++l) {
    k_transform<false><<<NBLK, 256, 0, stream>>>(hin, Wl + l*256, xl);
    k_aggregate<false><<<NBLK, 256, 0, stream>>>(hin, xl, Wr + l*256, att + l*16,
                                                 bias + l*16, offs, srcl, hout);
    const float* tmp = hout; hout = (float*)hin; hin = tmp;
  }
  // after 4 layers: hin == hB (final h)
  k_agg<<<NB, 1024, 0, stream>>>(hin, Wg1, bg1, Wg2, bg2, aggb);
  k_final<<<NB, 256, 0, stream>>>(hin, agent, nbr, aggb,
                                  We1, be1, We2, be2, We3, be3, out);
}